// Round 2
// baseline (975.784 us; speedup 1.0000x reference)
//
#include <hip/hip_runtime.h>

// Problem constants
#define NPOS   524288         // 8*16*64*64
#define KCODES 512
#define CDIM   64
#define THW    65536          // 16*64*64
#define MPOS   256            // positions per block
#define QCH    256            // codes per LDS chunk
#define NTHR   256

// out layout (float32): [0, 33554432) quantized BCTHW; [33554432] loss; [33554433, +524288) indices
#define QOUT_N   33554432L
#define LOSS_OFF 33554432L
#define IDX_OFF  33554433L

// ws layout: byte 0: double loss accumulator; byte 256: float ee[512]

// ---------- pre-kernel: ee[q] = sum_c e[q][c]^2, numpy pairwise-8 order ----------
extern "C" __global__ void vq_ee(const float* __restrict__ emb, float* __restrict__ ee) {
    int q = threadIdx.x;               // 512 threads
    const float* er = emb + q * 64;
    float r[8];
    #pragma unroll
    for (int j = 0; j < 8; ++j) { float v = er[j]; r[j] = __fmul_rn(v, v); }
    #pragma unroll
    for (int t = 1; t < 8; ++t)
        #pragma unroll
        for (int j = 0; j < 8; ++j) { float v = er[t * 8 + j]; r[j] = __fadd_rn(r[j], __fmul_rn(v, v)); }
    float s0 = __fadd_rn(__fadd_rn(r[0], r[1]), __fadd_rn(r[2], r[3]));
    float s1 = __fadd_rn(__fadd_rn(r[4], r[5]), __fadd_rn(r[6], r[7]));
    ee[q] = __fadd_rn(s0, s1);
}

// LDS (floats): a[64*256]=16384 | el[256*64]=16384 | ff[256] | idx[256]
// total 33280 floats = 133120 B (1 block/CU)

extern "C" __global__ __launch_bounds__(NTHR, 1)
void vq_main(const float* __restrict__ x, const float* __restrict__ emb,
             float* __restrict__ out, double* __restrict__ lossws,
             const float* __restrict__ eeg) {
    extern __shared__ float lds[];
    float* a    = lds;                 // [64][256], a[c*256+p]
    float* el   = lds + 16384;         // [256][64], float4-unit-swizzled: phys u = logical u ^ (row&15)
    float* ffl  = lds + 32768;         // [256]
    int*   idxl = (int*)(lds + 33024); // [256]

    const int tid = threadIdx.x;
    const int blk = blockIdx.x;
    const long n0 = (long)blk * MPOS;
    const int  b  = blk >> 8;                   // 256 blocks per batch element
    const long r0 = (long)(blk & 255) * MPOS;

    const float* xb = x + (long)b * CDIM * THW + r0;

    // ---- stage A-tile [64][256] via global_load_lds (16B), linear dest
    #pragma unroll
    for (int k = 0; k < 16; ++k) {
        int g = tid + NTHR * k;                 // float4-unit index 0..4095
        int c = g >> 6, p4 = g & 63;
        __builtin_amdgcn_global_load_lds(
            (const __attribute__((address_space(1))) void*)(xb + (long)c * THW + p4 * 4),
            (__attribute__((address_space(3))) void*)(a + g * 4), 16, 0, 0);
    }
    // ---- stage E chunk 0: linear dest, pre-swizzled global source (rule #21)
    {
        const float* eb = emb;
        #pragma unroll
        for (int k = 0; k < 16; ++k) {
            int g = tid + NTHR * k;             // 0..4095
            int row = g >> 4, p = g & 15;       // physical unit p of row
            int lu = p ^ (row & 15);            // logical float4 unit
            __builtin_amdgcn_global_load_lds(
                (const __attribute__((address_space(1))) void*)(eb + row * 64 + lu * 4),
                (__attribute__((address_space(3))) void*)(el + g * 4), 16, 0, 0);
        }
    }
    __syncthreads();   // drains vmcnt; a + el(ch0) ready

    // ---- ff[p] = sum_c f_c^2, numpy pairwise-8 (thread tid -> position tid)
    {
        float r[8];
        #pragma unroll
        for (int j = 0; j < 8; ++j) { float v = a[j * 256 + tid]; r[j] = __fmul_rn(v, v); }
        #pragma unroll
        for (int t = 1; t < 8; ++t)
            #pragma unroll
            for (int j = 0; j < 8; ++j) {
                float v = a[(t * 8 + j) * 256 + tid];
                r[j] = __fadd_rn(r[j], __fmul_rn(v, v));
            }
        float s0 = __fadd_rn(__fadd_rn(r[0], r[1]), __fadd_rn(r[2], r[3]));
        float s1 = __fadd_rn(__fadd_rn(r[4], r[5]), __fadd_rn(r[6], r[7]));
        ffl[tid] = __fadd_rn(s0, s1);
    }
    __syncthreads();

    const int w     = tid >> 6;        // wave id: positions [w*64, w*64+64)
    const int cg    = tid & 15;        // code lane 0..15
    const int pg    = (tid >> 4) & 3;  // position sub-group
    const int pbase = w * 64 + pg * 16;

    float dmin[16]; int kmin[16];
    #pragma unroll
    for (int j = 0; j < 16; ++j) { dmin[j] = 1e30f; kmin[j] = 0; }

    for (int ch = 0; ch < 2; ++ch) {
        if (ch) {
            __syncthreads();   // everyone done reading el chunk 0
            const float* eb = emb + QCH * 64;
            #pragma unroll
            for (int k = 0; k < 16; ++k) {
                int g = tid + NTHR * k;
                int row = g >> 4, p = g & 15;
                int lu = p ^ (row & 15);
                __builtin_amdgcn_global_load_lds(
                    (const __attribute__((address_space(1))) void*)(eb + row * 64 + lu * 4),
                    (__attribute__((address_space(3))) void*)(el + g * 4), 16, 0, 0);
            }
            __syncthreads();   // el chunk 1 ready
        }

        // ---- dot: acc[j][i] += f[pbase+j][c] * e[cg+16i][c], c strictly ascending
        float acc[16][16];
        #pragma unroll
        for (int j = 0; j < 16; ++j)
            #pragma unroll
            for (int i = 0; i < 16; ++i) acc[j][i] = 0.f;

        #pragma unroll 1
        for (int u = 0; u < 16; ++u) {          // c = 4u..4u+3
            float4 af4[4][4];                   // [cc][j4]
            #pragma unroll
            for (int cc = 0; cc < 4; ++cc)
                #pragma unroll
                for (int j4 = 0; j4 < 4; ++j4)
                    af4[cc][j4] = *(const float4*)(a + (u * 4 + cc) * 256 + pbase + j4 * 4);
            const int swz = (/*phys unit*/ 0 ^ 0, ((u ^ cg) << 2));  // row&15 == cg
            #pragma unroll
            for (int i = 0; i < 16; ++i) {
                int row = cg + 16 * i;
                float4 ev = *(const float4*)(el + row * 64 + swz);
                #pragma unroll
                for (int cc = 0; cc < 4; ++cc) {
                    float e = (cc == 0) ? ev.x : (cc == 1) ? ev.y : (cc == 2) ? ev.z : ev.w;
                    #pragma unroll
                    for (int j = 0; j < 16; ++j) {
                        float av = ((const float*)&af4[cc][j >> 2])[j & 3];
                        acc[j][i] = __fmaf_rn(av, e, acc[j][i]);
                    }
                }
            }
        }

        // ---- distances + running min (codes ascending: i asc within thread, ch asc)
        float eev[16];
        #pragma unroll
        for (int i = 0; i < 16; ++i) eev[i] = eeg[ch * QCH + cg + 16 * i];
        #pragma unroll
        for (int j = 0; j < 16; ++j) {
            float ffv = ffl[pbase + j];
            #pragma unroll
            for (int i = 0; i < 16; ++i) {
                float d = __fsub_rn(__fadd_rn(ffv, eev[i]), __fmul_rn(2.0f, acc[j][i]));
                int q = ch * QCH + cg + 16 * i;
                if (d < dmin[j]) { dmin[j] = d; kmin[j] = q; }
            }
        }
    }

    // ---- cross-lane argmin within each 16-lane code group (lowest-index tie-break)
    #pragma unroll
    for (int j = 0; j < 16; ++j) {
        #pragma unroll
        for (int m = 1; m <= 8; m <<= 1) {
            float od = __shfl_xor(dmin[j], m, 64);
            int   ok = __shfl_xor(kmin[j], m, 64);
            if (od < dmin[j] || (od == dmin[j] && ok < kmin[j])) { dmin[j] = od; kmin[j] = ok; }
        }
        if (cg == 0) idxl[pbase + j] = kmin[j];
    }
    __syncthreads();

    // ---- indices out (as float)
    out[IDX_OFF + n0 + tid] = (float)idxl[tid];

    // ---- quantized out (straight-through) + loss partial
    double lacc = 0.0;
    {
        const int col = (tid & 63) * 4;         // this thread's 4 positions (fixed across k)
        int iv[4];
        #pragma unroll
        for (int jj = 0; jj < 4; ++jj) iv[jj] = idxl[col + jj];
        float* ob = out + (long)b * CDIM * THW + r0;
        #pragma unroll
        for (int k = 0; k < 16; ++k) {
            int c = w + 4 * k;
            float4 xv = *(const float4*)(a + c * 256 + col);
            float4 ov;
            float q0 = emb[iv[0] * 64 + c];
            float d0 = __fsub_rn(q0, xv.x); ov.x = __fadd_rn(xv.x, d0); lacc += (double)__fmul_rn(d0, d0);
            float q1 = emb[iv[1] * 64 + c];
            float d1 = __fsub_rn(q1, xv.y); ov.y = __fadd_rn(xv.y, d1); lacc += (double)__fmul_rn(d1, d1);
            float q2 = emb[iv[2] * 64 + c];
            float d2 = __fsub_rn(q2, xv.z); ov.z = __fadd_rn(xv.z, d2); lacc += (double)__fmul_rn(d2, d2);
            float q3 = emb[iv[3] * 64 + c];
            float d3 = __fsub_rn(q3, xv.w); ov.w = __fadd_rn(xv.w, d3); lacc += (double)__fmul_rn(d3, d3);
            *(float4*)(ob + (long)c * THW + col) = ov;
        }
    }
    // wave reduce then block reduce loss
    #pragma unroll
    for (int m = 1; m < 64; m <<= 1) lacc += __shfl_xor(lacc, m, 64);
    double* wsum = (double*)ffl;  // ffl dead after chunk epilogues; 8B-aligned
    const int lane = tid & 63;
    if (lane == 0) wsum[w] = lacc;
    __syncthreads();
    if (tid == 0) {
        double s = wsum[0] + wsum[1] + wsum[2] + wsum[3];
        atomicAdd(lossws, s);
    }
}

extern "C" __global__ void vq_finalize(const double* __restrict__ lossws,
                                       float* __restrict__ out) {
    if (threadIdx.x == 0) {
        float m = (float)(lossws[0] / (double)QOUT_N);
        out[LOSS_OFF] = __fadd_rn(m, __fmul_rn(0.025f, m));
    }
}

extern "C" void kernel_launch(void* const* d_in, const int* in_sizes, int n_in,
                              void* d_out, int out_size, void* d_ws, size_t ws_size,
                              hipStream_t stream) {
    const float* x   = (const float*)d_in[0];
    const float* emb = (const float*)d_in[1];
    float* out = (float*)d_out;
    double* loss_ws = (double*)d_ws;
    float* ee_ws = (float*)((char*)d_ws + 256);

    hipMemsetAsync(d_ws, 0, sizeof(double), stream);
    hipLaunchKernelGGL(vq_ee, dim3(1), dim3(KCODES), 0, stream, emb, ee_ws);

    dim3 grid(NPOS / MPOS);   // 2048
    dim3 block(NTHR);
    size_t shmem = (16384 + 16384 + 256 + 256) * sizeof(float);  // 133120 B
    hipLaunchKernelGGL(vq_main, grid, block, shmem, stream, x, emb, out, loss_ws, ee_ws);
    hipLaunchKernelGGL(vq_finalize, dim3(1), dim3(1), 0, stream,
                       (const double*)loss_ws, out);
}

// Round 3
// 647.791 us; speedup vs baseline: 1.5063x; 1.5063x over previous
//
#include <hip/hip_runtime.h>

// Problem constants
#define NPOS   524288         // 8*16*64*64
#define KCODES 512
#define CDIM   64
#define THW    65536          // 16*64*64
#define MPOS   256            // positions per block
#define QCH    256            // codes per LDS chunk
#define NTHR   512            // 8 waves

// out layout (float32): [0, 33554432) quantized BCTHW; [33554432] loss; [33554433, +524288) indices
#define QOUT_N   33554432L
#define LOSS_OFF 33554432L
#define IDX_OFF  33554433L

// ws layout: byte 0: double loss accumulator; byte 256: float ee[512]

// ---------- pre-kernel: ee[q] = sum_c e[q][c]^2, numpy pairwise-8 order ----------
extern "C" __global__ void vq_ee(const float* __restrict__ emb, float* __restrict__ ee) {
    int q = threadIdx.x;               // 512 threads
    const float* er = emb + q * 64;
    float r[8];
    #pragma unroll
    for (int j = 0; j < 8; ++j) { float v = er[j]; r[j] = __fmul_rn(v, v); }
    #pragma unroll
    for (int t = 1; t < 8; ++t)
        #pragma unroll
        for (int j = 0; j < 8; ++j) { float v = er[t * 8 + j]; r[j] = __fadd_rn(r[j], __fmul_rn(v, v)); }
    float s0 = __fadd_rn(__fadd_rn(r[0], r[1]), __fadd_rn(r[2], r[3]));
    float s1 = __fadd_rn(__fadd_rn(r[4], r[5]), __fadd_rn(r[6], r[7]));
    ee[q] = __fadd_rn(s0, s1);
}

// LDS (floats): a[64*256]=16384 | el[256*64]=16384 (xor-swizzled) | ff[256] | idx[256]
// total 33280 floats = 133120 B -> 1 block/CU, 8 waves = 2/SIMD

extern "C" __global__ __launch_bounds__(NTHR, 2)
void vq_main(const float* __restrict__ x, const float* __restrict__ emb,
             float* __restrict__ out, double* __restrict__ lossws,
             const float* __restrict__ eeg) {
    extern __shared__ float lds[];
    float* a    = lds;                 // [64][256], a[c*256+p]
    float* el   = lds + 16384;         // [256][64], phys float4-unit = logical u ^ (row&15)
    float* ffl  = lds + 32768;         // [256]
    int*   idxl = (int*)(lds + 33024); // [256]

    const int tid = threadIdx.x;
    const int blk = blockIdx.x;
    const long n0 = (long)blk * MPOS;
    const int  b  = blk >> 8;                   // 256 blocks per batch element
    const long r0 = (long)(blk & 255) * MPOS;

    const float* xb = x + (long)b * CDIM * THW + r0;

    // ---- stage A-tile [64][256] via global_load_lds (16B), linear dest
    #pragma unroll
    for (int k = 0; k < 8; ++k) {
        int g = tid + NTHR * k;                 // float4-unit index 0..4095
        int c = g >> 6, p4 = g & 63;
        __builtin_amdgcn_global_load_lds(
            (const __attribute__((address_space(1))) void*)(xb + (long)c * THW + p4 * 4),
            (__attribute__((address_space(3))) void*)(a + g * 4), 16, 0, 0);
    }
    // ---- stage E chunk 0: linear dest, pre-swizzled global source
    #pragma unroll
    for (int k = 0; k < 8; ++k) {
        int g = tid + NTHR * k;                 // 0..4095
        int row = g >> 4, p = g & 15;           // physical unit p of row
        int lu = p ^ (row & 15);                // logical float4 unit
        __builtin_amdgcn_global_load_lds(
            (const __attribute__((address_space(1))) void*)(emb + row * 64 + lu * 4),
            (__attribute__((address_space(3))) void*)(el + g * 4), 16, 0, 0);
    }
    __syncthreads();   // drains vmcnt; a + el(ch0) ready

    // ---- ff[p] = sum_c f_c^2, numpy pairwise-8 (threads 0..255 -> position tid)
    if (tid < 256) {
        float r[8];
        #pragma unroll
        for (int j = 0; j < 8; ++j) { float v = a[j * 256 + tid]; r[j] = __fmul_rn(v, v); }
        #pragma unroll
        for (int t = 1; t < 8; ++t)
            #pragma unroll
            for (int j = 0; j < 8; ++j) {
                float v = a[(t * 8 + j) * 256 + tid];
                r[j] = __fadd_rn(r[j], __fmul_rn(v, v));
            }
        float s0 = __fadd_rn(__fadd_rn(r[0], r[1]), __fadd_rn(r[2], r[3]));
        float s1 = __fadd_rn(__fadd_rn(r[4], r[5]), __fadd_rn(r[6], r[7]));
        ffl[tid] = __fadd_rn(s0, s1);
    }
    __syncthreads();

    const int w     = tid >> 6;        // wave id 0..7: positions [w*32, w*32+32)
    const int lane  = tid & 63;
    const int cg    = lane & 15;       // code lane 0..15
    const int pg    = lane >> 4;       // position sub-group 0..3
    const int pbase = w * 32 + pg * 8; // 8 positions per thread

    float dmin[8]; int kmin[8];
    #pragma unroll
    for (int j = 0; j < 8; ++j) { dmin[j] = 1e30f; kmin[j] = 0; }

    for (int ch = 0; ch < 2; ++ch) {
        if (ch) {
            __syncthreads();   // everyone done reading el chunk 0
            const float* eb = emb + QCH * 64;
            #pragma unroll
            for (int k = 0; k < 8; ++k) {
                int g = tid + NTHR * k;
                int row = g >> 4, p = g & 15;
                int lu = p ^ (row & 15);
                __builtin_amdgcn_global_load_lds(
                    (const __attribute__((address_space(1))) void*)(eb + row * 64 + lu * 4),
                    (__attribute__((address_space(3))) void*)(el + g * 4), 16, 0, 0);
            }
            __syncthreads();   // el chunk 1 ready
        }

        // ---- dot: acc[j][i] += f[pbase+j][c] * e[cg+16i][c], c strictly ascending per acc
        float acc[8][16];
        #pragma unroll
        for (int j = 0; j < 8; ++j)
            #pragma unroll
            for (int i = 0; i < 16; ++i) acc[j][i] = 0.f;

        #pragma unroll 1
        for (int u = 0; u < 16; ++u) {          // c = 4u..4u+3
            float af[4][8];
            #pragma unroll
            for (int cc = 0; cc < 4; ++cc) {
                #pragma unroll
                for (int j2 = 0; j2 < 2; ++j2) {
                    float4 v = *(const float4*)(a + (u * 4 + cc) * 256 + pbase + j2 * 4);
                    af[cc][j2 * 4 + 0] = v.x; af[cc][j2 * 4 + 1] = v.y;
                    af[cc][j2 * 4 + 2] = v.z; af[cc][j2 * 4 + 3] = v.w;
                }
            }
            #pragma unroll
            for (int i = 0; i < 16; ++i) {
                int row = cg + 16 * i;
                float4 ev = *(const float4*)(el + row * 64 + ((u ^ cg) << 2));
                #pragma unroll
                for (int j = 0; j < 8; ++j) acc[j][i] = __fmaf_rn(af[0][j], ev.x, acc[j][i]);
                #pragma unroll
                for (int j = 0; j < 8; ++j) acc[j][i] = __fmaf_rn(af[1][j], ev.y, acc[j][i]);
                #pragma unroll
                for (int j = 0; j < 8; ++j) acc[j][i] = __fmaf_rn(af[2][j], ev.z, acc[j][i]);
                #pragma unroll
                for (int j = 0; j < 8; ++j) acc[j][i] = __fmaf_rn(af[3][j], ev.w, acc[j][i]);
            }
        }

        // ---- distances + running min (codes ascending: i asc within thread, ch asc)
        float eev[16];
        #pragma unroll
        for (int i = 0; i < 16; ++i) eev[i] = eeg[ch * QCH + cg + 16 * i];
        #pragma unroll
        for (int j = 0; j < 8; ++j) {
            float ffv = ffl[pbase + j];
            #pragma unroll
            for (int i = 0; i < 16; ++i) {
                float d = __fsub_rn(__fadd_rn(ffv, eev[i]), __fmul_rn(2.0f, acc[j][i]));
                int q = ch * QCH + cg + 16 * i;
                if (d < dmin[j]) { dmin[j] = d; kmin[j] = q; }
            }
        }
    }

    // ---- cross-lane argmin within each 16-lane code group (lowest-index tie-break)
    #pragma unroll
    for (int j = 0; j < 8; ++j) {
        #pragma unroll
        for (int m = 1; m <= 8; m <<= 1) {
            float od = __shfl_xor(dmin[j], m, 64);
            int   ok = __shfl_xor(kmin[j], m, 64);
            if (od < dmin[j] || (od == dmin[j] && ok < kmin[j])) { dmin[j] = od; kmin[j] = ok; }
        }
        if (cg == 0) idxl[pbase + j] = kmin[j];
    }
    __syncthreads();

    // ---- indices out (as float)
    if (tid < 256) out[IDX_OFF + n0 + tid] = (float)idxl[tid];

    // ---- quantized out (straight-through) + loss partial
    double lacc = 0.0;
    {
        const int col = (tid & 63) * 4;         // this thread's 4 positions
        int iv[4];
        #pragma unroll
        for (int jj = 0; jj < 4; ++jj) iv[jj] = idxl[col + jj];
        float* ob = out + (long)b * CDIM * THW + r0;
        #pragma unroll
        for (int k = 0; k < 8; ++k) {
            int c = (tid >> 6) + 8 * k;
            float4 xv = *(const float4*)(a + c * 256 + col);
            float4 ov;
            float q0 = emb[iv[0] * 64 + c];
            float d0 = __fsub_rn(q0, xv.x); ov.x = __fadd_rn(xv.x, d0); lacc += (double)__fmul_rn(d0, d0);
            float q1 = emb[iv[1] * 64 + c];
            float d1 = __fsub_rn(q1, xv.y); ov.y = __fadd_rn(xv.y, d1); lacc += (double)__fmul_rn(d1, d1);
            float q2 = emb[iv[2] * 64 + c];
            float d2 = __fsub_rn(q2, xv.z); ov.z = __fadd_rn(xv.z, d2); lacc += (double)__fmul_rn(d2, d2);
            float q3 = emb[iv[3] * 64 + c];
            float d3 = __fsub_rn(q3, xv.w); ov.w = __fadd_rn(xv.w, d3); lacc += (double)__fmul_rn(d3, d3);
            *(float4*)(ob + (long)c * THW + col) = ov;
        }
    }
    // wave reduce then block reduce loss
    #pragma unroll
    for (int m = 1; m < 64; m <<= 1) lacc += __shfl_xor(lacc, m, 64);
    double* wsum = (double*)ffl;  // ffl dead after distance phase; 8B-aligned
    if ((tid & 63) == 0) wsum[w] = lacc;
    __syncthreads();
    if (tid == 0) {
        double s = 0.0;
        #pragma unroll
        for (int i = 0; i < 8; ++i) s += wsum[i];
        atomicAdd(lossws, s);
    }
}

extern "C" __global__ void vq_finalize(const double* __restrict__ lossws,
                                       float* __restrict__ out) {
    if (threadIdx.x == 0) {
        float m = (float)(lossws[0] / (double)QOUT_N);
        out[LOSS_OFF] = __fadd_rn(m, __fmul_rn(0.025f, m));
    }
}

extern "C" void kernel_launch(void* const* d_in, const int* in_sizes, int n_in,
                              void* d_out, int out_size, void* d_ws, size_t ws_size,
                              hipStream_t stream) {
    const float* x   = (const float*)d_in[0];
    const float* emb = (const float*)d_in[1];
    float* out = (float*)d_out;
    double* loss_ws = (double*)d_ws;
    float* ee_ws = (float*)((char*)d_ws + 256);

    hipMemsetAsync(d_ws, 0, sizeof(double), stream);
    hipLaunchKernelGGL(vq_ee, dim3(1), dim3(KCODES), 0, stream, emb, ee_ws);

    dim3 grid(NPOS / MPOS);   // 2048
    dim3 block(NTHR);
    size_t shmem = (16384 + 16384 + 256 + 256) * sizeof(float);  // 133120 B
    hipLaunchKernelGGL(vq_main, grid, block, shmem, stream, x, emb, out, loss_ws, ee_ws);
    hipLaunchKernelGGL(vq_finalize, dim3(1), dim3(1), 0, stream,
                       (const double*)loss_ws, out);
}

// Round 4
// 528.856 us; speedup vs baseline: 1.8451x; 1.2249x over previous
//
#include <hip/hip_runtime.h>

typedef float f32x2 __attribute__((ext_vector_type(2)));
typedef float f32x4 __attribute__((ext_vector_type(4)));

// Problem constants
#define NPOS   524288         // 8*16*64*64
#define KCODES 512
#define CDIM   64
#define THW    65536          // 16*64*64
#define MPOS   256            // positions per block
#define QCH    256            // codes per LDS chunk
#define NTHR   512            // 8 waves

// out layout (float32): [0, 33554432) quantized BCTHW; [33554432] loss; [33554433, +524288) indices
#define QOUT_N   33554432L
#define LOSS_OFF 33554432L
#define IDX_OFF  33554433L

// packed fp32 FMA: both halves are IEEE fp32 FMA; e word broadcast via op_sel.
// LO: both result halves use word0 of e-pair. HI: both use word1.
#define PK_FMA_E_LO(acc, a2, e2) \
    asm("v_pk_fma_f32 %0, %1, %2, %0 op_sel_hi:[1,0,1]" : "+v"(acc) : "v"(a2), "v"(e2))
#define PK_FMA_E_HI(acc, a2, e2) \
    asm("v_pk_fma_f32 %0, %1, %2, %0 op_sel:[0,1,0] op_sel_hi:[1,1,1]" : "+v"(acc) : "v"(a2), "v"(e2))

// ---------- pre-kernel: ee[q] = sum_c e[q][c]^2, numpy pairwise-8 order ----------
extern "C" __global__ void vq_ee(const float* __restrict__ emb, float* __restrict__ ee) {
    int q = threadIdx.x;               // 512 threads
    const float* er = emb + q * 64;
    float r[8];
    #pragma unroll
    for (int j = 0; j < 8; ++j) { float v = er[j]; r[j] = __fmul_rn(v, v); }
    #pragma unroll
    for (int t = 1; t < 8; ++t)
        #pragma unroll
        for (int j = 0; j < 8; ++j) { float v = er[t * 8 + j]; r[j] = __fadd_rn(r[j], __fmul_rn(v, v)); }
    float s0 = __fadd_rn(__fadd_rn(r[0], r[1]), __fadd_rn(r[2], r[3]));
    float s1 = __fadd_rn(__fadd_rn(r[4], r[5]), __fadd_rn(r[6], r[7]));
    ee[q] = __fadd_rn(s0, s1);
}

// LDS (floats): a[64*256]=16384 | el[256*64]=16384 (xor-swizzled) | ff[256] | idx[256]
// total 33280 floats = 133120 B -> 1 block/CU, 8 waves = 2/SIMD

extern "C" __global__ __launch_bounds__(NTHR, 1)
void vq_main(const float* __restrict__ x, const float* __restrict__ emb,
             float* __restrict__ out, double* __restrict__ lossws,
             const float* __restrict__ eeg) {
    extern __shared__ float lds[];
    float* a    = lds;                 // [64][256], a[c*256+p]
    float* el   = lds + 16384;         // [256][64], phys float4-unit = logical u ^ (row&15)
    float* ffl  = lds + 32768;         // [256]
    int*   idxl = (int*)(lds + 33024); // [256]

    const int tid = threadIdx.x;
    const int blk = blockIdx.x;
    const long n0 = (long)blk * MPOS;
    const int  b  = blk >> 8;                   // 256 blocks per batch element
    const long r0 = (long)(blk & 255) * MPOS;

    const float* xb = x + (long)b * CDIM * THW + r0;

    // ---- stage A-tile [64][256] via global_load_lds (16B), linear dest
    #pragma unroll
    for (int k = 0; k < 8; ++k) {
        int g = tid + NTHR * k;                 // float4-unit index 0..4095
        int c = g >> 6, p4 = g & 63;
        __builtin_amdgcn_global_load_lds(
            (const __attribute__((address_space(1))) void*)(xb + (long)c * THW + p4 * 4),
            (__attribute__((address_space(3))) void*)(a + g * 4), 16, 0, 0);
    }
    // ---- stage E chunk 0: linear dest, pre-swizzled global source
    #pragma unroll
    for (int k = 0; k < 8; ++k) {
        int g = tid + NTHR * k;                 // 0..4095
        int row = g >> 4, p = g & 15;           // physical unit p of row
        int lu = p ^ (row & 15);                // logical float4 unit
        __builtin_amdgcn_global_load_lds(
            (const __attribute__((address_space(1))) void*)(emb + row * 64 + lu * 4),
            (__attribute__((address_space(3))) void*)(el + g * 4), 16, 0, 0);
    }
    __syncthreads();   // drains vmcnt; a + el(ch0) ready

    // ---- ff[p] = sum_c f_c^2, numpy pairwise-8 (threads 0..255 -> position tid)
    if (tid < 256) {
        float r[8];
        #pragma unroll
        for (int j = 0; j < 8; ++j) { float v = a[j * 256 + tid]; r[j] = __fmul_rn(v, v); }
        #pragma unroll
        for (int t = 1; t < 8; ++t)
            #pragma unroll
            for (int j = 0; j < 8; ++j) {
                float v = a[(t * 8 + j) * 256 + tid];
                r[j] = __fadd_rn(r[j], __fmul_rn(v, v));
            }
        float s0 = __fadd_rn(__fadd_rn(r[0], r[1]), __fadd_rn(r[2], r[3]));
        float s1 = __fadd_rn(__fadd_rn(r[4], r[5]), __fadd_rn(r[6], r[7]));
        ffl[tid] = __fadd_rn(s0, s1);
    }
    __syncthreads();

    const int w     = tid >> 6;        // wave id 0..7: positions [w*32, w*32+32)
    const int lane  = tid & 63;
    const int cg    = lane & 15;       // code lane 0..15
    const int pg    = lane >> 4;       // position sub-group 0..3
    const int pbase = w * 32 + pg * 8; // 8 positions per thread

    float dmin[8]; int kmin[8];
    #pragma unroll
    for (int j = 0; j < 8; ++j) { dmin[j] = 1e30f; kmin[j] = 0; }

    for (int ch = 0; ch < 2; ++ch) {
        if (ch) {
            __syncthreads();   // everyone done reading el chunk 0
            const float* eb = emb + QCH * 64;
            #pragma unroll
            for (int k = 0; k < 8; ++k) {
                int g = tid + NTHR * k;
                int row = g >> 4, p = g & 15;
                int lu = p ^ (row & 15);
                __builtin_amdgcn_global_load_lds(
                    (const __attribute__((address_space(1))) void*)(eb + row * 64 + lu * 4),
                    (__attribute__((address_space(3))) void*)(el + g * 4), 16, 0, 0);
            }
            __syncthreads();   // el chunk 1 ready
        }

        // ---- dot: acc2[jp][i] (pos pair 2jp,2jp+1) += a * e, c strictly ascending per half
        f32x2 acc2[4][16];
        #pragma unroll
        for (int jp = 0; jp < 4; ++jp)
            #pragma unroll
            for (int i = 0; i < 16; ++i) acc2[jp][i] = (f32x2){0.f, 0.f};

        #pragma unroll 1
        for (int u = 0; u < 16; ++u) {          // c = 4u..4u+3
            // a pairs: af2[cc][jp] = positions (pbase+2jp, pbase+2jp+1) at c=4u+cc
            f32x2 af2[4][4];
            #pragma unroll
            for (int cc = 0; cc < 4; ++cc) {
                f32x4 v0 = *(const f32x4*)(a + (u * 4 + cc) * 256 + pbase);
                f32x4 v1 = *(const f32x4*)(a + (u * 4 + cc) * 256 + pbase + 4);
                af2[cc][0] = v0.xy; af2[cc][1] = v0.zw;
                af2[cc][2] = v1.xy; af2[cc][3] = v1.zw;
            }
            #pragma unroll
            for (int i = 0; i < 16; ++i) {
                int row = cg + 16 * i;
                f32x4 ev = *(const f32x4*)(el + row * 64 + ((u ^ cg) << 2));
                f32x2 e01 = ev.xy, e23 = ev.zw;
                #pragma unroll
                for (int jp = 0; jp < 4; ++jp) PK_FMA_E_LO(acc2[jp][i], af2[0][jp], e01);
                #pragma unroll
                for (int jp = 0; jp < 4; ++jp) PK_FMA_E_HI(acc2[jp][i], af2[1][jp], e01);
                #pragma unroll
                for (int jp = 0; jp < 4; ++jp) PK_FMA_E_LO(acc2[jp][i], af2[2][jp], e23);
                #pragma unroll
                for (int jp = 0; jp < 4; ++jp) PK_FMA_E_HI(acc2[jp][i], af2[3][jp], e23);
            }
        }

        // ---- distances + running min (codes ascending: i asc within thread, ch asc)
        float eev[16];
        #pragma unroll
        for (int i = 0; i < 16; ++i) eev[i] = eeg[ch * QCH + cg + 16 * i];
        #pragma unroll
        for (int j = 0; j < 8; ++j) {
            float ffv = ffl[pbase + j];
            #pragma unroll
            for (int i = 0; i < 16; ++i) {
                float accv = (j & 1) ? acc2[j >> 1][i].y : acc2[j >> 1][i].x;
                // fl(2*acc) is exact, so fma(acc,-2,t1) == fl(t1 - fl(2*acc)) bit-exact
                float t1 = __fadd_rn(ffv, eev[i]);
                float d  = __fmaf_rn(accv, -2.0f, t1);
                int q = ch * QCH + cg + 16 * i;
                if (d < dmin[j]) { dmin[j] = d; kmin[j] = q; }
            }
        }
    }

    // ---- cross-lane argmin within each 16-lane code group (lowest-index tie-break)
    #pragma unroll
    for (int j = 0; j < 8; ++j) {
        #pragma unroll
        for (int m = 1; m <= 8; m <<= 1) {
            float od = __shfl_xor(dmin[j], m, 64);
            int   ok = __shfl_xor(kmin[j], m, 64);
            if (od < dmin[j] || (od == dmin[j] && ok < kmin[j])) { dmin[j] = od; kmin[j] = ok; }
        }
        if (cg == 0) idxl[pbase + j] = kmin[j];
    }
    __syncthreads();

    // ---- indices out (as float)
    if (tid < 256) out[IDX_OFF + n0 + tid] = (float)idxl[tid];

    // ---- quantized out (straight-through) + loss partial
    double lacc = 0.0;
    {
        const int col = (tid & 63) * 4;         // this thread's 4 positions
        int iv[4];
        #pragma unroll
        for (int jj = 0; jj < 4; ++jj) iv[jj] = idxl[col + jj];
        float* ob = out + (long)b * CDIM * THW + r0;
        #pragma unroll
        for (int k = 0; k < 8; ++k) {
            int c = (tid >> 6) + 8 * k;
            float4 xv = *(const float4*)(a + c * 256 + col);
            float4 ov;
            float q0 = emb[iv[0] * 64 + c];
            float d0 = __fsub_rn(q0, xv.x); ov.x = __fadd_rn(xv.x, d0); lacc += (double)__fmul_rn(d0, d0);
            float q1 = emb[iv[1] * 64 + c];
            float d1 = __fsub_rn(q1, xv.y); ov.y = __fadd_rn(xv.y, d1); lacc += (double)__fmul_rn(d1, d1);
            float q2 = emb[iv[2] * 64 + c];
            float d2 = __fsub_rn(q2, xv.z); ov.z = __fadd_rn(xv.z, d2); lacc += (double)__fmul_rn(d2, d2);
            float q3 = emb[iv[3] * 64 + c];
            float d3 = __fsub_rn(q3, xv.w); ov.w = __fadd_rn(xv.w, d3); lacc += (double)__fmul_rn(d3, d3);
            *(float4*)(ob + (long)c * THW + col) = ov;
        }
    }
    // wave reduce then block reduce loss
    #pragma unroll
    for (int m = 1; m < 64; m <<= 1) lacc += __shfl_xor(lacc, m, 64);
    double* wsum = (double*)ffl;  // ffl dead after distance phase; 8B-aligned
    if ((tid & 63) == 0) wsum[w] = lacc;
    __syncthreads();
    if (tid == 0) {
        double s = 0.0;
        #pragma unroll
        for (int i = 0; i < 8; ++i) s += wsum[i];
        atomicAdd(lossws, s);
    }
}

extern "C" __global__ void vq_finalize(const double* __restrict__ lossws,
                                       float* __restrict__ out) {
    if (threadIdx.x == 0) {
        float m = (float)(lossws[0] / (double)QOUT_N);
        out[LOSS_OFF] = __fadd_rn(m, __fmul_rn(0.025f, m));
    }
}

extern "C" void kernel_launch(void* const* d_in, const int* in_sizes, int n_in,
                              void* d_out, int out_size, void* d_ws, size_t ws_size,
                              hipStream_t stream) {
    const float* x   = (const float*)d_in[0];
    const float* emb = (const float*)d_in[1];
    float* out = (float*)d_out;
    double* loss_ws = (double*)d_ws;
    float* ee_ws = (float*)((char*)d_ws + 256);

    hipMemsetAsync(d_ws, 0, sizeof(double), stream);
    hipLaunchKernelGGL(vq_ee, dim3(1), dim3(KCODES), 0, stream, emb, ee_ws);

    dim3 grid(NPOS / MPOS);   // 2048
    dim3 block(NTHR);
    size_t shmem = (16384 + 16384 + 256 + 256) * sizeof(float);  // 133120 B
    hipLaunchKernelGGL(vq_main, grid, block, shmem, stream, x, emb, out, loss_ws, ee_ws);
    hipLaunchKernelGGL(vq_finalize, dim3(1), dim3(1), 0, stream,
                       (const double*)loss_ws, out);
}